// Round 17
// baseline (233.105 us; speedup 1.0000x reference)
//
#include <hip/hip_runtime.h>
#include <hip/hip_bf16.h>
#include <math.h>

#define HEADS 4
#define HID 32
#define EMB 32
#define SLOPE 0.2f
#define BN_EPS 1e-5f
#define BNUM 256   // bucket array size (actual B = ceil(N/512) <= 256)
#define P 256      // radix blocks

typedef __attribute__((ext_vector_type(8))) short short8;   // 8 bf16 (4 VGPRs)
typedef __attribute__((ext_vector_type(4))) float fx4;      // 4 fp32 accumulator

__device__ __forceinline__ float lrelu(float x) { return x > 0.f ? x : SLOPE * x; }
__device__ __forceinline__ float elu(float x) { return x > 0.f ? x : expm1f(x); }

// RNE float->bf16 and pack/unpack helpers
__device__ __forceinline__ unsigned f2bf_pack(float a, float b) {
    unsigned ua = __float_as_uint(a);
    unsigned ub = __float_as_uint(b);
    unsigned ra = (ua + 0x7fffu + ((ua >> 16) & 1u)) >> 16;
    unsigned rb = (ub + 0x7fffu + ((ub >> 16) & 1u)) >> 16;
    return ra | (rb << 16);
}
__device__ __forceinline__ float bf_lo(unsigned p) { return __uint_as_float(p << 16); }
__device__ __forceinline__ float bf_hi(unsigned p) { return __uint_as_float(p & 0xffff0000u); }

union BfFrag { unsigned u[4]; short8 v; };

// ---------------- tiny prep: Ms[2][4], Md[2][4] = per-head dot(W1 row, attn vec) ----------------
__global__ void k_prep(const float* __restrict__ W1, const float* __restrict__ as1,
                       const float* __restrict__ ad1, float* __restrict__ MsMd) {
    int t = threadIdx.x;
    if (t >= 16) return;
    int r = (t >> 2) & 1, h = t & 3;
    const float* a = (t >= 8) ? ad1 : as1;
    float s = 0.f;
#pragma unroll
    for (int d = 0; d < 32; d++) s += W1[r * 128 + h * 32 + d] * a[h * 32 + d];
    MsMd[t] = s;
}

// ---------------- pass A: per-block histogram, p-major ghist[p][b] ----------------
__global__ void __launch_bounds__(256) k_hist(const int* __restrict__ ei,
                                              int* __restrict__ ghist, int E_, int CH) {
    __shared__ int h[BNUM];
    int t = threadIdx.x, p = blockIdx.x;
    h[t] = 0;
    __syncthreads();
    int beg = p * CH, end = beg + CH;
    if (end > E_) end = E_;
    for (int e = beg + t; e < end; e += 256) atomicAdd(&h[ei[E_ + e] >> 9], 1);
    __syncthreads();
    ghist[p * BNUM + t] = h[t];  // coalesced
}

// ---------------- pass B: exclusive scan of ghist in bucket-major order ----------------
__global__ void __launch_bounds__(1024) k_gscan(const int* __restrict__ ghist,
                                                int* __restrict__ goff, int* __restrict__ sbase,
                                                int* __restrict__ rp, int N_, int E_) {
    __shared__ int s[1024];
    int t = threadIdx.x;
    const int PER = (BNUM * P) / 1024;  // 64
    int b0 = t >> 2;
    int p0 = (t & 3) * PER;
    int v[PER];
    int sum = 0;
#pragma unroll
    for (int k = 0; k < PER; k++) {
        v[k] = ghist[(p0 + k) * BNUM + b0];
        sum += v[k];
    }
    s[t] = sum;
    __syncthreads();
    for (int off = 1; off < 1024; off <<= 1) {
        int a = (t >= off) ? s[t - off] : 0;
        __syncthreads();
        s[t] += a;
        __syncthreads();
    }
    int run = s[t] - sum;
#pragma unroll
    for (int k = 0; k < PER; k++) {
        if (p0 + k == 0) sbase[b0] = run;
        goff[(p0 + k) * BNUM + b0] = run;
        run += v[k];
    }
    if (t == 0) {
        sbase[BNUM] = E_;
        rp[N_] = E_ + N_;
    }
}

// ---------------- pass C: scatter into block-private per-bucket ranges ----------------
__global__ void __launch_bounds__(256) k_scatter3(const int* __restrict__ ei,
                                                  const int* __restrict__ goff,
                                                  unsigned* __restrict__ staged,
                                                  int E_, int CH) {
    __shared__ int loff[BNUM];
    __shared__ int lpos[BNUM];
    int t = threadIdx.x, p = blockIdx.x;
    loff[t] = goff[p * BNUM + t];
    lpos[t] = 0;
    __syncthreads();
    int beg = p * CH, end = beg + CH;
    if (end > E_) end = E_;
    for (int e = beg + t; e < end; e += 256) {
        int s = ei[e], d = ei[E_ + e];
        int b = d >> 9;
        unsigned pk = ((unsigned)s << 9) | (unsigned)(d & 511);
        int pos = loff[b] + atomicAdd(&lpos[b], 1);
        staged[pos] = pk;
    }
}

// ---------------- per-bucket finalize: count, scan, write rp + esrc (+self loops) -------
__global__ void __launch_bounds__(512) k_bucket(const unsigned* __restrict__ staged,
                                                const int* __restrict__ sbase,
                                                int* __restrict__ rp, int* __restrict__ esrc,
                                                int N_) {
    int b = blockIdx.x;
    int n0 = b << 9;
    int nn = N_ - n0;
    if (nn > 512) nn = 512;
    if (nn <= 0) return;
    __shared__ int lc[512];
    __shared__ int sc[512];
    __shared__ int wpos[512];
    int t = threadIdx.x;
    lc[t] = 0;
    __syncthreads();
    int sb = sbase[b];
    int m = sbase[b + 1] - sb;
    int eb = sb + (b << 9);
    for (int i = t; i < m; i += 512) atomicAdd(&lc[staged[sb + i] & 511], 1);
    __syncthreads();
    sc[t] = lc[t];
    __syncthreads();
    for (int off = 1; off < 512; off <<= 1) {
        int a = (t >= off) ? sc[t - off] : 0;
        __syncthreads();
        sc[t] += a;
        __syncthreads();
    }
    if (t < nn) {
        int r = eb + (sc[t] - lc[t]) + t;
        rp[n0 + t] = r;
        wpos[t] = r;
        esrc[r + lc[t]] = n0 + t;          // self loop at final slot (no atomic)
    }
    __syncthreads();
    for (int i = t; i < m; i += 512) {
        unsigned p = staged[sb + i];
        int q = atomicAdd(&wpos[p & 511], 1);
        esrc[q] = (int)(p >> 9);
    }
}

// ---------------- layer 1 aggregation, FACTORIZED + fused BN1 moment partials ----------
// 4 lanes per node (lane = head). Emits nsum[node][8] and per-block 20 moment partials
// (5 per head) via wave shuffle (stride 4..32 keeps head in lane bits 0-1) + LDS tree.
__global__ void __launch_bounds__(256) k_agg1f(
        const float* __restrict__ x, const int* __restrict__ rp,
        const int* __restrict__ esrc, const float* __restrict__ MsMd,
        float* __restrict__ nsum, float* __restrict__ mpart, int n) {
    __shared__ float sM[16];
    __shared__ float lsm[4][4][5];   // [wave][head][moment]
    int t = threadIdx.x;
    if (t < 16) sM[t] = MsMd[t];
    __syncthreads();
    int node = blockIdx.x * 64 + (t >> 2);
    int h = t & 3;
    float sxv = 0.f, syv = 0.f;
    if (node < n) {
        int beg = rp[node], end = rp[node + 1];
        const float2 xd = *reinterpret_cast<const float2*>(&x[(size_t)node * 2]);
        float ald = xd.x * sM[8 + h] + xd.y * sM[12 + h];
        float ms0 = sM[h], ms1 = sM[4 + h];
        float z = 0.f, sx = 0.f, sy = 0.f;
#pragma unroll 2
        for (int e = beg; e < end; e++) {
            int s = esrc[e];
            float2 xs = *reinterpret_cast<const float2*>(&x[(size_t)s * 2]);
            float al = xs.x * ms0 + xs.y * ms1;
            float w = __expf(lrelu(al + ald));
            z += w;
            sx = fmaf(w, xs.x, sx);
            sy = fmaf(w, xs.y, sy);
        }
        float inv = 1.f / (z + 1e-16f);
        sxv = sx * inv;
        syv = sy * inv;
        nsum[(size_t)node * 8 + h] = sxv;
        nsum[(size_t)node * 8 + 4 + h] = syv;
    }
    // ---- fused BN1 moments (invalid nodes contribute zeros) ----
    float m0 = sxv, m1 = syv, m2 = sxv * sxv, m3 = syv * syv, m4 = sxv * syv;
#pragma unroll
    for (int off = 4; off < 64; off <<= 1) {
        m0 += __shfl_xor(m0, off);
        m1 += __shfl_xor(m1, off);
        m2 += __shfl_xor(m2, off);
        m3 += __shfl_xor(m3, off);
        m4 += __shfl_xor(m4, off);
    }
    int lane = t & 63, wave = t >> 6;
    if (lane < 4) {
        lsm[wave][lane][0] = m0;
        lsm[wave][lane][1] = m1;
        lsm[wave][lane][2] = m2;
        lsm[wave][lane][3] = m3;
        lsm[wave][lane][4] = m4;
    }
    __syncthreads();
    if (t < 20) {
        int hh = t / 5, j = t % 5;
        mpart[(size_t)blockIdx.x * 20 + t] =
            lsm[0][hh][j] + lsm[1][hh][j] + lsm[2][hh][j] + lsm[3][hh][j];
    }
}

// ---------------- BN1 finalize: parallel reduce of block moments -> per-channel P,Q,R ----
// 640 threads: 32 rows x 20 moments, then 20-wide LDS sum, then 128 channels.
__global__ void __launch_bounds__(640) k_bn1fin(
        const float* __restrict__ mpart, const float* __restrict__ W1,
        const float* __restrict__ b1, const float* __restrict__ g1,
        const float* __restrict__ be1, float4* __restrict__ PQR, int n, int nb) {
    __shared__ float ls[20][32];
    __shared__ float mom[20];
    int t = threadIdx.x;
    if (t < 640) {
        int j = t % 20, r = t / 20;
        float s = 0.f;
        for (int b = r; b < nb; b += 32) s += mpart[(size_t)b * 20 + j];
        ls[j][r] = s;
    }
    __syncthreads();
    if (t < 20) {
        float s = 0.f;
#pragma unroll
        for (int r = 0; r < 32; r++) s += ls[t][r];
        mom[t] = s;
    }
    __syncthreads();
    if (t < 128) {
        int c = t, h = c >> 5;
        float invn = 1.f / (float)n;
        float mx = mom[h * 5 + 0] * invn, my = mom[h * 5 + 1] * invn;
        float mxx = mom[h * 5 + 2] * invn, myy = mom[h * 5 + 3] * invn;
        float mxy = mom[h * 5 + 4] * invn;
        float w0 = W1[c], w1 = W1[128 + c], bb = b1[c];
        float mu = w0 * mx + w1 * my + bb;
        float ex2 = w0 * w0 * mxx + w1 * w1 * myy + 2.f * w0 * w1 * mxy
                  + 2.f * bb * (w0 * mx + w1 * my) + bb * bb;
        float var = ex2 - mu * mu;
        float A = g1[c] * rsqrtf(var + BN_EPS);
        float B = be1[c] - mu * A;
        PQR[c] = make_float4(A * w0, A * w1, A * bb + B, 0.f);
    }
}

// ---------------- layer 2 node transform via MFMA ----------------------------------------
// Per wave: 16-node tile. A = Y[16 x 128] built in registers (yk = elu(P*sx+Q*sy+R), bf16);
// B = W2[128 x 32] as two 16-col tiles (bf16, from L1). 8x mfma_f32_16x16x32_bf16, fp32 acc.
__global__ void __launch_bounds__(256) k_node2m(
        const float* __restrict__ nsum, const float4* __restrict__ PQR,
        const float* __restrict__ W2, const float* __restrict__ as2,
        const float* __restrict__ ad2, unsigned* __restrict__ h2bf,
        float* __restrict__ als2, float* __restrict__ ald2, int n) {
    int t = threadIdx.x;
    int wave = t >> 6, lane = t & 63;
    int col = lane & 15;     // A-row (node) for A-build; channel for B/D
    int kgrp = lane >> 4;    // 0..3
    int nb = blockIdx.x * 64 + wave * 16;
    if (nb >= n) return;
    int nodeA = nb + col;
    float4 sx4 = make_float4(0.f, 0.f, 0.f, 0.f), sy4 = sx4;
    if (nodeA < n) {
        sx4 = *reinterpret_cast<const float4*>(&nsum[(size_t)nodeA * 8]);
        sy4 = *reinterpret_cast<const float4*>(&nsum[(size_t)nodeA * 8 + 4]);
    }
    BfFrag b1f[4], b2f[4];
#pragma unroll
    for (int kblk = 0; kblk < 4; kblk++) {
#pragma unroll
        for (int j = 0; j < 8; j += 2) {
            int k = kblk * 32 + kgrp * 8 + j;
            b1f[kblk].u[j >> 1] = f2bf_pack(W2[k * 32 + col], W2[(k + 1) * 32 + col]);
            b2f[kblk].u[j >> 1] = f2bf_pack(W2[k * 32 + 16 + col], W2[(k + 1) * 32 + 16 + col]);
        }
    }
    fx4 acc1 = {0.f, 0.f, 0.f, 0.f};
    fx4 acc2 = {0.f, 0.f, 0.f, 0.f};
    float sxh, syh;
#pragma unroll
    for (int kblk = 0; kblk < 4; kblk++) {
        if (kblk == 0) { sxh = sx4.x; syh = sy4.x; }
        else if (kblk == 1) { sxh = sx4.y; syh = sy4.y; }
        else if (kblk == 2) { sxh = sx4.z; syh = sy4.z; }
        else { sxh = sx4.w; syh = sy4.w; }
        BfFrag af;
        float yk[8];
#pragma unroll
        for (int j = 0; j < 8; j++) {
            int k = kblk * 32 + kgrp * 8 + j;
            float4 pqr = PQR[k];
            yk[j] = elu(fmaf(pqr.x, sxh, fmaf(pqr.y, syh, pqr.z)));
        }
#pragma unroll
        for (int j = 0; j < 8; j += 2) af.u[j >> 1] = f2bf_pack(yk[j], yk[j + 1]);
        acc1 = __builtin_amdgcn_mfma_f32_16x16x32_bf16(af.v, b1f[kblk].v, acc1, 0, 0, 0);
        acc2 = __builtin_amdgcn_mfma_f32_16x16x32_bf16(af.v, b2f[kblk].v, acc2, 0, 0, 0);
    }
    float a2c = as2[col], a2c2 = as2[16 + col];
    float d2c = ad2[col], d2c2 = ad2[16 + col];
#pragma unroll
    for (int r = 0; r < 4; r++) {
        int node = nb + kgrp * 4 + r;
        float v1 = acc1[r], v2 = acc2[r];
        float pS = v1 * a2c + v2 * a2c2;
        float pD = v1 * d2c + v2 * d2c2;
#pragma unroll
        for (int off = 1; off < 16; off <<= 1) {
            pS += __shfl_xor(pS, off);
            pD += __shfl_xor(pD, off);
        }
        float v1n = __shfl_xor(v1, 1);
        float v2n = __shfl_xor(v2, 1);
        if (node < n) {
            if ((col & 1) == 0) {
                h2bf[(size_t)node * 16 + (col >> 1)] = f2bf_pack(v1, v1n);
                h2bf[(size_t)node * 16 + 8 + (col >> 1)] = f2bf_pack(v2, v2n);
            }
            if (col == 0) { als2[node] = pS; ald2[node] = pD; }
        }
    }
}

// ---------------- BN stats stage 2: parallel finalize (512 threads) ----------------
__global__ void k_stats2(const float* __restrict__ partials, const float* __restrict__ gamma,
                         const float* __restrict__ beta, float* __restrict__ AB,
                         int n, int C, int nb) {
    __shared__ float ls[512], ls2[512];
    int t = threadIdx.x;
    int R = 512 / C;
    int c = t & (C - 1);
    int r = t / C;
    float s = 0.f, s2 = 0.f;
    for (int b = r; b < nb; b += R) {
        s += partials[(size_t)b * 2 * C + c];
        s2 += partials[(size_t)b * 2 * C + C + c];
    }
    ls[t] = s;
    ls2[t] = s2;
    __syncthreads();
    for (int step = R >> 1; step > 0; step >>= 1) {
        if (r < step) {
            ls[t] += ls[t + step * C];
            ls2[t] += ls2[t + step * C];
        }
        __syncthreads();
    }
    if (r == 0) {
        float mu = ls[t] / n;
        float var = ls2[t] / n - mu * mu;
        float inv = rsqrtf(var + BN_EPS);
        float A = gamma[c] * inv;
        AB[c] = A;
        AB[C + c] = beta[c] - mu * A;
    }
}

// ---------------- layer 2 aggregation + fused BN2 partials ------------------------------
// 8-lane group per dst node, uint2 bf16 gather; per-block deterministic LDS tree reduces
// sum/sumsq of outputs over the block's 32 nodes into partials[blk][64].
__global__ void __launch_bounds__(256) k_agg2(
        const unsigned* __restrict__ h2bf, const float* __restrict__ als2,
        const float* __restrict__ ald2, const int* __restrict__ rp,
        const int* __restrict__ esrc, const float* __restrict__ b2,
        float* __restrict__ out, float* __restrict__ partials, int n) {
    __shared__ int ss2[4][8][9];    // pad 9 -> group broadcasts on disjoint banks
    __shared__ float swv[4][8][9];
    __shared__ float red[8][33][4];   // [e][nodeSlot][i], padded
    __shared__ float red2[8][33][4];
    int wslot = threadIdx.x >> 6;
    int lane = threadIdx.x & 63;
    int g = lane >> 3;       // group within wave
    int e = lane & 7;        // lane within group: dwords 2e,2e+1 of the row
    int wid = blockIdx.x * 32 + wslot * 8 + g;
    float4 o = make_float4(0.f, 0.f, 0.f, 0.f);
    if (wid < n) {
        int beg = rp[wid], end = rp[wid + 1];
        float ad = ald2[wid];
        float a0 = 0.f, a1 = 0.f, a2 = 0.f, a3 = 0.f;
        float z = 0.f;
        const uint2* __restrict__ hrow = reinterpret_cast<const uint2*>(h2bf);
        for (int cb = beg; cb < end; cb += 8) {
            int cnt = end - cb;
            if (cnt > 8) cnt = 8;
            if (e < cnt) {
                int s = esrc[cb + e];
                ss2[wslot][g][e] = s;
                swv[wslot][g][e] = __expf(lrelu(als2[s] + ad));
            }
            int j = 0;
            for (; j + 4 <= cnt; j += 4) {
                int s0 = ss2[wslot][g][j];
                int s1 = ss2[wslot][g][j + 1];
                int s2 = ss2[wslot][g][j + 2];
                int s3 = ss2[wslot][g][j + 3];
                float w0 = swv[wslot][g][j];
                float w1 = swv[wslot][g][j + 1];
                float w2 = swv[wslot][g][j + 2];
                float w3 = swv[wslot][g][j + 3];
                uint2 p0 = hrow[(size_t)s0 * 8 + e];
                uint2 p1 = hrow[(size_t)s1 * 8 + e];
                uint2 p2 = hrow[(size_t)s2 * 8 + e];
                uint2 p3 = hrow[(size_t)s3 * 8 + e];
                z += w0 + w1 + w2 + w3;
                a0 = fmaf(w0, bf_lo(p0.x), a0); a1 = fmaf(w0, bf_hi(p0.x), a1);
                a2 = fmaf(w0, bf_lo(p0.y), a2); a3 = fmaf(w0, bf_hi(p0.y), a3);
                a0 = fmaf(w1, bf_lo(p1.x), a0); a1 = fmaf(w1, bf_hi(p1.x), a1);
                a2 = fmaf(w1, bf_lo(p1.y), a2); a3 = fmaf(w1, bf_hi(p1.y), a3);
                a0 = fmaf(w2, bf_lo(p2.x), a0); a1 = fmaf(w2, bf_hi(p2.x), a1);
                a2 = fmaf(w2, bf_lo(p2.y), a2); a3 = fmaf(w2, bf_hi(p2.y), a3);
                a0 = fmaf(w3, bf_lo(p3.x), a0); a1 = fmaf(w3, bf_hi(p3.x), a1);
                a2 = fmaf(w3, bf_lo(p3.y), a2); a3 = fmaf(w3, bf_hi(p3.y), a3);
            }
            for (; j < cnt; j++) {
                int s = ss2[wslot][g][j];
                float wgt = swv[wslot][g][j];
                z += wgt;
                uint2 p = hrow[(size_t)s * 8 + e];
                a0 = fmaf(wgt, bf_lo(p.x), a0);
                a1 = fmaf(wgt, bf_hi(p.x), a1);
                a2 = fmaf(wgt, bf_lo(p.y), a2);
                a3 = fmaf(wgt, bf_hi(p.y), a3);
            }
        }
        float inv = 1.f / (z + 1e-16f);   // z uniform across the 8-lane group
        const float4 bv = *reinterpret_cast<const float4*>(&b2[4 * e]);
        o = make_float4(a0 * inv + bv.x, a1 * inv + bv.y, a2 * inv + bv.z, a3 * inv + bv.w);
        *reinterpret_cast<float4*>(&out[(size_t)wid * 32 + 4 * e]) = o;
    }
    // ---- fused BN2 partials (deterministic tree over the block's 32 node slots) ----
    int ns = wslot * 8 + g;
    red[e][ns][0] = o.x; red[e][ns][1] = o.y; red[e][ns][2] = o.z; red[e][ns][3] = o.w;
    red2[e][ns][0] = o.x * o.x; red2[e][ns][1] = o.y * o.y;
    red2[e][ns][2] = o.z * o.z; red2[e][ns][3] = o.w * o.w;
    __syncthreads();
    for (int step = 16; step > 0; step >>= 1) {
        if (ns < step) {
#pragma unroll
            for (int i = 0; i < 4; i++) {
                red[e][ns][i] += red[e][ns + step][i];
                red2[e][ns][i] += red2[e][ns + step][i];
            }
        }
        __syncthreads();
    }
    if (ns == 0) {
#pragma unroll
        for (int i = 0; i < 4; i++) {
            partials[(size_t)blockIdx.x * 64 + 4 * e + i] = red[e][0][i];
            partials[(size_t)blockIdx.x * 64 + 32 + 4 * e + i] = red2[e][0][i];
        }
    }
}

// ---------------- BN2+ELU + mean pool + classifier: wave per graph (inline bounds) -------
__global__ void k_pool(const float* __restrict__ x, const float* __restrict__ AB2,
                       const int* __restrict__ batch, const float* __restrict__ Wc,
                       const float* __restrict__ bc, float* __restrict__ out, int n, int G_) {
    int wid = (blockIdx.x * blockDim.x + threadIdx.x) >> 6;
    int lane = threadIdx.x & 63;
    if (wid >= G_) return;
    int lo = 0, hi = n;
    while (lo < hi) {
        int mid = (lo + hi) >> 1;
        if (batch[mid] < wid) lo = mid + 1; else hi = mid;
    }
    int beg = lo;
    hi = n;
    while (lo < hi) {
        int mid = (lo + hi) >> 1;
        if (batch[mid] < wid + 1) lo = mid + 1; else hi = mid;
    }
    int end = lo;
    int half = lane >> 5, f = lane & 31;
    float A = AB2[f], B = AB2[32 + f];
    float acc = 0.f;
    for (int r = beg + half; r < end; r += 2) {
        float v = x[(size_t)r * 32 + f] * A + B;
        acc += elu(v);
    }
    acc += __shfl_xor(acc, 32);
    float cntf = (float)((end - beg) > 1 ? (end - beg) : 1);
    float embv = acc / cntf;
    float p0 = embv * Wc[f * 2], p1 = embv * Wc[f * 2 + 1];
#pragma unroll
    for (int o = 1; o < 32; o <<= 1) {
        p0 += __shfl_xor(p0, o);
        p1 += __shfl_xor(p1, o);
    }
    if (lane == 0) {
        out[wid * 2] = p0 + bc[0];
        out[wid * 2 + 1] = p1 + bc[1];
    }
}

extern "C" void kernel_launch(void* const* d_in, const int* in_sizes, int n_in,
                              void* d_out, int out_size, void* d_ws, size_t ws_size,
                              hipStream_t stream) {
    const float* x = (const float*)d_in[0];
    const int* ei = (const int*)d_in[1];
    const int* batch = (const int*)d_in[2];
    const float* W1 = (const float*)d_in[3];
    const float* as1 = (const float*)d_in[4];
    const float* ad1 = (const float*)d_in[5];
    const float* b1 = (const float*)d_in[6];
    const float* g1 = (const float*)d_in[7];
    const float* be1 = (const float*)d_in[8];
    const float* W2 = (const float*)d_in[9];
    const float* as2 = (const float*)d_in[10];
    const float* ad2 = (const float*)d_in[11];
    const float* b2 = (const float*)d_in[12];
    const float* g2 = (const float*)d_in[13];
    const float* be2 = (const float*)d_in[14];
    const float* Wc = (const float*)d_in[15];
    const float* bc = (const float*)d_in[16];
    float* out = (float*)d_out;

    const int N = in_sizes[0] / 2;
    const int E = in_sizes[1] / 2;
    const int G = out_size / 2;
    const int Etot = E + N;
    const int B = (N + 511) >> 9;     // buckets of 512 dst nodes (<= 256)
    const int CH = (E + P - 1) / P;   // edges per radix block
    const int NB1 = (N + 63) / 64;    // agg1f blocks (moment partials)
    const int NB2 = (N + 31) / 32;    // agg2 blocks (BN2 partials)

    // workspace layout
    char* w = (char*)d_ws;
    size_t off = 0;
    auto alloc = [&](size_t bytes) { void* p = w + off; off = (off + bytes + 255) & ~(size_t)255; return p; };
    float* nsum = (float*)alloc((size_t)N * 8 * 4);          // per-node (sx[4], sy[4])
    unsigned* l2buf = (unsigned*)alloc((size_t)N * 50 * 4);  // h2bf + als2 + ald2 + out2
    int* esrc = (int*)alloc((size_t)Etot * 4);
    unsigned* staged = (unsigned*)alloc((size_t)E * 4);
    int* rp = (int*)alloc((size_t)(N + 1) * 4);
    int* ghist = (int*)alloc((size_t)P * BNUM * 4);
    int* goff = (int*)alloc((size_t)P * BNUM * 4);
    int* sbase = (int*)alloc((BNUM + 1) * 4);
    float* partials = (float*)alloc((size_t)NB2 * 64 * 4);
    float* mpart = (float*)alloc((size_t)NB1 * 20 * 4);
    float* AB2 = (float*)alloc(64 * 4);
    float* MsMd = (float*)alloc(64 * 4);
    float4* PQR = (float4*)alloc(128 * 16);
    unsigned* h2bf = l2buf;                                  // N*16 uints (N x 32 bf16)
    float* als2 = (float*)(l2buf + (size_t)N * 16);          // N floats
    float* ald2 = (float*)(l2buf + (size_t)N * 17);          // N floats
    float* out2 = (float*)(l2buf + (size_t)N * 18);          // N*32 floats

    // 1. tiny prep: factorized attention matrices
    k_prep<<<1, 64, 0, stream>>>(W1, as1, ad1, MsMd);
    // 2. radix pass A: per-block histograms
    k_hist<<<P, 256, 0, stream>>>(ei, ghist, E, CH);
    // 3. radix pass B: bucket-major exclusive scan -> goff, sbase, rp[N]
    k_gscan<<<1, 1024, 0, stream>>>(ghist, goff, sbase, rp, N, E);
    // 4. radix pass C: scatter to block-private ranges
    k_scatter3<<<P, 256, 0, stream>>>(ei, goff, staged, E, CH);
    // 5. per-bucket finalize: rp + esrc (+self loops)
    k_bucket<<<B, 512, 0, stream>>>(staged, sbase, rp, esrc, N);
    // 6. layer 1 aggregation + fused BN1 moment partials
    k_agg1f<<<NB1, 256, 0, stream>>>(x, rp, esrc, MsMd, nsum, mpart, N);
    // 7. BN1 finalize (parallel): per-channel P,Q,R
    k_bn1fin<<<1, 640, 0, stream>>>(mpart, W1, b1, g1, be1, PQR, N, NB1);
    // 8. layer 2 node transform: MFMA (16-node tile per wave)
    k_node2m<<<(N + 63) / 64, 256, 0, stream>>>(nsum, PQR, W2, as2, ad2, h2bf, als2, ald2, N);
    // 9. layer 2 aggregation + fused BN2 partials
    k_agg2<<<NB2, 256, 0, stream>>>(h2bf, als2, ald2, rp, esrc, b2, out2, partials, N);
    // 10. BN2 finalize
    k_stats2<<<1, 512, 0, stream>>>(partials, g2, be2, AB2, N, 32, NB2);
    // 11. BN2+ELU + pool + classifier (bounds inline)
    k_pool<<<(G * 64 + 255) / 256, 256, 0, stream>>>(out2, AB2, batch, Wc, bc, out, N, G);
}

// Round 18
// 187.897 us; speedup vs baseline: 1.2406x; 1.2406x over previous
//
#include <hip/hip_runtime.h>
#include <hip/hip_bf16.h>
#include <math.h>

#define HEADS 4
#define HID 32
#define EMB 32
#define SLOPE 0.2f
#define BN_EPS 1e-5f
#define BNUM 256   // bucket array size (actual B = ceil(N/512) <= 256)
#define P 256      // radix blocks

typedef __attribute__((ext_vector_type(8))) short short8;   // 8 bf16 (4 VGPRs)
typedef __attribute__((ext_vector_type(4))) float fx4;      // 4 fp32 accumulator

__device__ __forceinline__ float lrelu(float x) { return x > 0.f ? x : SLOPE * x; }
__device__ __forceinline__ float elu(float x) { return x > 0.f ? x : expm1f(x); }

// RNE float->bf16 and pack/unpack helpers
__device__ __forceinline__ unsigned f2bf_pack(float a, float b) {
    unsigned ua = __float_as_uint(a);
    unsigned ub = __float_as_uint(b);
    unsigned ra = (ua + 0x7fffu + ((ua >> 16) & 1u)) >> 16;
    unsigned rb = (ub + 0x7fffu + ((ub >> 16) & 1u)) >> 16;
    return ra | (rb << 16);
}
__device__ __forceinline__ float bf_lo(unsigned p) { return __uint_as_float(p << 16); }
__device__ __forceinline__ float bf_hi(unsigned p) { return __uint_as_float(p & 0xffff0000u); }

union BfFrag { unsigned u[4]; short8 v; };

// ---------------- tiny prep: Ms[2][4], Md[2][4] = per-head dot(W1 row, attn vec) ----------------
__global__ void k_prep(const float* __restrict__ W1, const float* __restrict__ as1,
                       const float* __restrict__ ad1, float* __restrict__ MsMd) {
    int t = threadIdx.x;
    if (t >= 16) return;
    int r = (t >> 2) & 1, h = t & 3;
    const float* a = (t >= 8) ? ad1 : as1;
    float s = 0.f;
#pragma unroll
    for (int d = 0; d < 32; d++) s += W1[r * 128 + h * 32 + d] * a[h * 32 + d];
    MsMd[t] = s;
}

// ---------------- pass A: per-block histogram, p-major ghist[p][b] ----------------
__global__ void __launch_bounds__(256) k_hist(const int* __restrict__ ei,
                                              int* __restrict__ ghist, int E_, int CH) {
    __shared__ int h[BNUM];
    int t = threadIdx.x, p = blockIdx.x;
    h[t] = 0;
    __syncthreads();
    int beg = p * CH, end = beg + CH;
    if (end > E_) end = E_;
    for (int e = beg + t; e < end; e += 256) atomicAdd(&h[ei[E_ + e] >> 9], 1);
    __syncthreads();
    ghist[p * BNUM + t] = h[t];  // coalesced
}

// ---------------- pass B: exclusive scan of ghist in bucket-major order ----------------
__global__ void __launch_bounds__(1024) k_gscan(const int* __restrict__ ghist,
                                                int* __restrict__ goff, int* __restrict__ sbase,
                                                int* __restrict__ rp, int N_, int E_) {
    __shared__ int s[1024];
    int t = threadIdx.x;
    const int PER = (BNUM * P) / 1024;  // 64
    int b0 = t >> 2;
    int p0 = (t & 3) * PER;
    int v[PER];
    int sum = 0;
#pragma unroll
    for (int k = 0; k < PER; k++) {
        v[k] = ghist[(p0 + k) * BNUM + b0];
        sum += v[k];
    }
    s[t] = sum;
    __syncthreads();
    for (int off = 1; off < 1024; off <<= 1) {
        int a = (t >= off) ? s[t - off] : 0;
        __syncthreads();
        s[t] += a;
        __syncthreads();
    }
    int run = s[t] - sum;
#pragma unroll
    for (int k = 0; k < PER; k++) {
        if (p0 + k == 0) sbase[b0] = run;
        goff[(p0 + k) * BNUM + b0] = run;
        run += v[k];
    }
    if (t == 0) {
        sbase[BNUM] = E_;
        rp[N_] = E_ + N_;
    }
}

// ---------------- pass C: scatter into block-private per-bucket ranges ----------------
__global__ void __launch_bounds__(256) k_scatter3(const int* __restrict__ ei,
                                                  const int* __restrict__ goff,
                                                  unsigned* __restrict__ staged,
                                                  int E_, int CH) {
    __shared__ int loff[BNUM];
    __shared__ int lpos[BNUM];
    int t = threadIdx.x, p = blockIdx.x;
    loff[t] = goff[p * BNUM + t];
    lpos[t] = 0;
    __syncthreads();
    int beg = p * CH, end = beg + CH;
    if (end > E_) end = E_;
    for (int e = beg + t; e < end; e += 256) {
        int s = ei[e], d = ei[E_ + e];
        int b = d >> 9;
        unsigned pk = ((unsigned)s << 9) | (unsigned)(d & 511);
        int pos = loff[b] + atomicAdd(&lpos[b], 1);
        staged[pos] = pk;
    }
}

// ---------------- per-bucket finalize: count, scan, write rp + esrc (+self loops) -------
__global__ void __launch_bounds__(512) k_bucket(const unsigned* __restrict__ staged,
                                                const int* __restrict__ sbase,
                                                int* __restrict__ rp, int* __restrict__ esrc,
                                                int N_) {
    int b = blockIdx.x;
    int n0 = b << 9;
    int nn = N_ - n0;
    if (nn > 512) nn = 512;
    if (nn <= 0) return;
    __shared__ int lc[512];
    __shared__ int sc[512];
    __shared__ int wpos[512];
    int t = threadIdx.x;
    lc[t] = 0;
    __syncthreads();
    int sb = sbase[b];
    int m = sbase[b + 1] - sb;
    int eb = sb + (b << 9);
    for (int i = t; i < m; i += 512) atomicAdd(&lc[staged[sb + i] & 511], 1);
    __syncthreads();
    sc[t] = lc[t];
    __syncthreads();
    for (int off = 1; off < 512; off <<= 1) {
        int a = (t >= off) ? sc[t - off] : 0;
        __syncthreads();
        sc[t] += a;
        __syncthreads();
    }
    if (t < nn) {
        int r = eb + (sc[t] - lc[t]) + t;
        rp[n0 + t] = r;
        wpos[t] = r;
        esrc[r + lc[t]] = n0 + t;          // self loop at final slot (no atomic)
    }
    __syncthreads();
    for (int i = t; i < m; i += 512) {
        unsigned p = staged[sb + i];
        int q = atomicAdd(&wpos[p & 511], 1);
        esrc[q] = (int)(p >> 9);
    }
}

// ---------------- layer 1 aggregation, FACTORIZED + fused BN1 moment partials ----------
__global__ void __launch_bounds__(256) k_agg1f(
        const float* __restrict__ x, const int* __restrict__ rp,
        const int* __restrict__ esrc, const float* __restrict__ MsMd,
        float* __restrict__ nsum, float* __restrict__ mpart, int n) {
    __shared__ float sM[16];
    __shared__ float lsm[4][4][5];   // [wave][head][moment]
    int t = threadIdx.x;
    if (t < 16) sM[t] = MsMd[t];
    __syncthreads();
    int node = blockIdx.x * 64 + (t >> 2);
    int h = t & 3;
    float sxv = 0.f, syv = 0.f;
    if (node < n) {
        int beg = rp[node], end = rp[node + 1];
        const float2 xd = *reinterpret_cast<const float2*>(&x[(size_t)node * 2]);
        float ald = xd.x * sM[8 + h] + xd.y * sM[12 + h];
        float ms0 = sM[h], ms1 = sM[4 + h];
        float z = 0.f, sx = 0.f, sy = 0.f;
#pragma unroll 2
        for (int e = beg; e < end; e++) {
            int s = esrc[e];
            float2 xs = *reinterpret_cast<const float2*>(&x[(size_t)s * 2]);
            float al = xs.x * ms0 + xs.y * ms1;
            float w = __expf(lrelu(al + ald));
            z += w;
            sx = fmaf(w, xs.x, sx);
            sy = fmaf(w, xs.y, sy);
        }
        float inv = 1.f / (z + 1e-16f);
        sxv = sx * inv;
        syv = sy * inv;
        nsum[(size_t)node * 8 + h] = sxv;
        nsum[(size_t)node * 8 + 4 + h] = syv;
    }
    // ---- fused BN1 moments (invalid nodes contribute zeros) ----
    float m0 = sxv, m1 = syv, m2 = sxv * sxv, m3 = syv * syv, m4 = sxv * syv;
#pragma unroll
    for (int off = 4; off < 64; off <<= 1) {
        m0 += __shfl_xor(m0, off);
        m1 += __shfl_xor(m1, off);
        m2 += __shfl_xor(m2, off);
        m3 += __shfl_xor(m3, off);
        m4 += __shfl_xor(m4, off);
    }
    int lane = t & 63, wave = t >> 6;
    if (lane < 4) {
        lsm[wave][lane][0] = m0;
        lsm[wave][lane][1] = m1;
        lsm[wave][lane][2] = m2;
        lsm[wave][lane][3] = m3;
        lsm[wave][lane][4] = m4;
    }
    __syncthreads();
    if (t < 20) {
        int hh = t / 5, j = t % 5;
        mpart[(size_t)blockIdx.x * 20 + t] =
            lsm[0][hh][j] + lsm[1][hh][j] + lsm[2][hh][j] + lsm[3][hh][j];
    }
}

// ---------------- BN1 finalize: parallel reduce of block moments -> per-channel P,Q,R ----
__global__ void __launch_bounds__(640) k_bn1fin(
        const float* __restrict__ mpart, const float* __restrict__ W1,
        const float* __restrict__ b1, const float* __restrict__ g1,
        const float* __restrict__ be1, float4* __restrict__ PQR, int n, int nb) {
    __shared__ float ls[20][32];
    __shared__ float mom[20];
    int t = threadIdx.x;
    if (t < 640) {
        int j = t % 20, r = t / 20;
        float s = 0.f;
        for (int b = r; b < nb; b += 32) s += mpart[(size_t)b * 20 + j];
        ls[j][r] = s;
    }
    __syncthreads();
    if (t < 20) {
        float s = 0.f;
#pragma unroll
        for (int r = 0; r < 32; r++) s += ls[t][r];
        mom[t] = s;
    }
    __syncthreads();
    if (t < 128) {
        int c = t, h = c >> 5;
        float invn = 1.f / (float)n;
        float mx = mom[h * 5 + 0] * invn, my = mom[h * 5 + 1] * invn;
        float mxx = mom[h * 5 + 2] * invn, myy = mom[h * 5 + 3] * invn;
        float mxy = mom[h * 5 + 4] * invn;
        float w0 = W1[c], w1 = W1[128 + c], bb = b1[c];
        float mu = w0 * mx + w1 * my + bb;
        float ex2 = w0 * w0 * mxx + w1 * w1 * myy + 2.f * w0 * w1 * mxy
                  + 2.f * bb * (w0 * mx + w1 * my) + bb * bb;
        float var = ex2 - mu * mu;
        float A = g1[c] * rsqrtf(var + BN_EPS);
        float B = be1[c] - mu * A;
        PQR[c] = make_float4(A * w0, A * w1, A * bb + B, 0.f);
    }
}

// ---------------- layer 2 node transform via MFMA ----------------------------------------
__global__ void __launch_bounds__(256) k_node2m(
        const float* __restrict__ nsum, const float4* __restrict__ PQR,
        const float* __restrict__ W2, const float* __restrict__ as2,
        const float* __restrict__ ad2, unsigned* __restrict__ h2bf,
        float* __restrict__ als2, float* __restrict__ ald2, int n) {
    int t = threadIdx.x;
    int wave = t >> 6, lane = t & 63;
    int col = lane & 15;     // A-row (node) for A-build; channel for B/D
    int kgrp = lane >> 4;    // 0..3
    int nb = blockIdx.x * 64 + wave * 16;
    if (nb >= n) return;
    int nodeA = nb + col;
    float4 sx4 = make_float4(0.f, 0.f, 0.f, 0.f), sy4 = sx4;
    if (nodeA < n) {
        sx4 = *reinterpret_cast<const float4*>(&nsum[(size_t)nodeA * 8]);
        sy4 = *reinterpret_cast<const float4*>(&nsum[(size_t)nodeA * 8 + 4]);
    }
    BfFrag b1f[4], b2f[4];
#pragma unroll
    for (int kblk = 0; kblk < 4; kblk++) {
#pragma unroll
        for (int j = 0; j < 8; j += 2) {
            int k = kblk * 32 + kgrp * 8 + j;
            b1f[kblk].u[j >> 1] = f2bf_pack(W2[k * 32 + col], W2[(k + 1) * 32 + col]);
            b2f[kblk].u[j >> 1] = f2bf_pack(W2[k * 32 + 16 + col], W2[(k + 1) * 32 + 16 + col]);
        }
    }
    fx4 acc1 = {0.f, 0.f, 0.f, 0.f};
    fx4 acc2 = {0.f, 0.f, 0.f, 0.f};
    float sxh, syh;
#pragma unroll
    for (int kblk = 0; kblk < 4; kblk++) {
        if (kblk == 0) { sxh = sx4.x; syh = sy4.x; }
        else if (kblk == 1) { sxh = sx4.y; syh = sy4.y; }
        else if (kblk == 2) { sxh = sx4.z; syh = sy4.z; }
        else { sxh = sx4.w; syh = sy4.w; }
        BfFrag af;
        float yk[8];
#pragma unroll
        for (int j = 0; j < 8; j++) {
            int k = kblk * 32 + kgrp * 8 + j;
            float4 pqr = PQR[k];
            yk[j] = elu(fmaf(pqr.x, sxh, fmaf(pqr.y, syh, pqr.z)));
        }
#pragma unroll
        for (int j = 0; j < 8; j += 2) af.u[j >> 1] = f2bf_pack(yk[j], yk[j + 1]);
        acc1 = __builtin_amdgcn_mfma_f32_16x16x32_bf16(af.v, b1f[kblk].v, acc1, 0, 0, 0);
        acc2 = __builtin_amdgcn_mfma_f32_16x16x32_bf16(af.v, b2f[kblk].v, acc2, 0, 0, 0);
    }
    float a2c = as2[col], a2c2 = as2[16 + col];
    float d2c = ad2[col], d2c2 = ad2[16 + col];
#pragma unroll
    for (int r = 0; r < 4; r++) {
        int node = nb + kgrp * 4 + r;
        float v1 = acc1[r], v2 = acc2[r];
        float pS = v1 * a2c + v2 * a2c2;
        float pD = v1 * d2c + v2 * d2c2;
#pragma unroll
        for (int off = 1; off < 16; off <<= 1) {
            pS += __shfl_xor(pS, off);
            pD += __shfl_xor(pD, off);
        }
        float v1n = __shfl_xor(v1, 1);
        float v2n = __shfl_xor(v2, 1);
        if (node < n) {
            if ((col & 1) == 0) {
                h2bf[(size_t)node * 16 + (col >> 1)] = f2bf_pack(v1, v1n);
                h2bf[(size_t)node * 16 + 8 + (col >> 1)] = f2bf_pack(v2, v2n);
            }
            if (col == 0) { als2[node] = pS; ald2[node] = pD; }
        }
    }
}

// ---------------- BN2 reduce stage A: 3125 block-partials -> mid[64][64] ----------------
__global__ void __launch_bounds__(256) k_red2(const float* __restrict__ partials,
                                              float* __restrict__ mid, int nb) {
    __shared__ float ls[256];
    int t = threadIdx.x;
    int c = t & 63, r = t >> 6;   // r in 0..3
    float s = 0.f;
    for (int b = blockIdx.x * 4 + r; b < nb; b += 256)
        s += partials[(size_t)b * 64 + c];
    ls[t] = s;
    __syncthreads();
    if (r == 0)
        mid[(size_t)blockIdx.x * 64 + c] = ls[c] + ls[64 + c] + ls[128 + c] + ls[192 + c];
}

// ---------------- BN stats stage 2: parallel finalize (512 threads) ----------------
__global__ void k_stats2(const float* __restrict__ partials, const float* __restrict__ gamma,
                         const float* __restrict__ beta, float* __restrict__ AB,
                         int n, int C, int nb) {
    __shared__ float ls[512], ls2[512];
    int t = threadIdx.x;
    int R = 512 / C;
    int c = t & (C - 1);
    int r = t / C;
    float s = 0.f, s2 = 0.f;
    for (int b = r; b < nb; b += R) {
        s += partials[(size_t)b * 2 * C + c];
        s2 += partials[(size_t)b * 2 * C + C + c];
    }
    ls[t] = s;
    ls2[t] = s2;
    __syncthreads();
    for (int step = R >> 1; step > 0; step >>= 1) {
        if (r < step) {
            ls[t] += ls[t + step * C];
            ls2[t] += ls2[t + step * C];
        }
        __syncthreads();
    }
    if (r == 0) {
        float mu = ls[t] / n;
        float var = ls2[t] / n - mu * mu;
        float inv = rsqrtf(var + BN_EPS);
        float A = gamma[c] * inv;
        AB[c] = A;
        AB[C + c] = beta[c] - mu * A;
    }
}

// ---------------- layer 2 aggregation + fused BN2 partials ------------------------------
__global__ void __launch_bounds__(256) k_agg2(
        const unsigned* __restrict__ h2bf, const float* __restrict__ als2,
        const float* __restrict__ ald2, const int* __restrict__ rp,
        const int* __restrict__ esrc, const float* __restrict__ b2,
        float* __restrict__ out, float* __restrict__ partials, int n) {
    __shared__ int ss2[4][8][9];    // pad 9 -> group broadcasts on disjoint banks
    __shared__ float swv[4][8][9];
    __shared__ float red[8][33][4];   // [e][nodeSlot][i], padded
    __shared__ float red2[8][33][4];
    int wslot = threadIdx.x >> 6;
    int lane = threadIdx.x & 63;
    int g = lane >> 3;       // group within wave
    int e = lane & 7;        // lane within group: dwords 2e,2e+1 of the row
    int wid = blockIdx.x * 32 + wslot * 8 + g;
    float4 o = make_float4(0.f, 0.f, 0.f, 0.f);
    if (wid < n) {
        int beg = rp[wid], end = rp[wid + 1];
        float ad = ald2[wid];
        float a0 = 0.f, a1 = 0.f, a2 = 0.f, a3 = 0.f;
        float z = 0.f;
        const uint2* __restrict__ hrow = reinterpret_cast<const uint2*>(h2bf);
        for (int cb = beg; cb < end; cb += 8) {
            int cnt = end - cb;
            if (cnt > 8) cnt = 8;
            if (e < cnt) {
                int s = esrc[cb + e];
                ss2[wslot][g][e] = s;
                swv[wslot][g][e] = __expf(lrelu(als2[s] + ad));
            }
            int j = 0;
            for (; j + 4 <= cnt; j += 4) {
                int s0 = ss2[wslot][g][j];
                int s1 = ss2[wslot][g][j + 1];
                int s2 = ss2[wslot][g][j + 2];
                int s3 = ss2[wslot][g][j + 3];
                float w0 = swv[wslot][g][j];
                float w1 = swv[wslot][g][j + 1];
                float w2 = swv[wslot][g][j + 2];
                float w3 = swv[wslot][g][j + 3];
                uint2 p0 = hrow[(size_t)s0 * 8 + e];
                uint2 p1 = hrow[(size_t)s1 * 8 + e];
                uint2 p2 = hrow[(size_t)s2 * 8 + e];
                uint2 p3 = hrow[(size_t)s3 * 8 + e];
                z += w0 + w1 + w2 + w3;
                a0 = fmaf(w0, bf_lo(p0.x), a0); a1 = fmaf(w0, bf_hi(p0.x), a1);
                a2 = fmaf(w0, bf_lo(p0.y), a2); a3 = fmaf(w0, bf_hi(p0.y), a3);
                a0 = fmaf(w1, bf_lo(p1.x), a0); a1 = fmaf(w1, bf_hi(p1.x), a1);
                a2 = fmaf(w1, bf_lo(p1.y), a2); a3 = fmaf(w1, bf_hi(p1.y), a3);
                a0 = fmaf(w2, bf_lo(p2.x), a0); a1 = fmaf(w2, bf_hi(p2.x), a1);
                a2 = fmaf(w2, bf_lo(p2.y), a2); a3 = fmaf(w2, bf_hi(p2.y), a3);
                a0 = fmaf(w3, bf_lo(p3.x), a0); a1 = fmaf(w3, bf_hi(p3.x), a1);
                a2 = fmaf(w3, bf_lo(p3.y), a2); a3 = fmaf(w3, bf_hi(p3.y), a3);
            }
            for (; j < cnt; j++) {
                int s = ss2[wslot][g][j];
                float wgt = swv[wslot][g][j];
                z += wgt;
                uint2 p = hrow[(size_t)s * 8 + e];
                a0 = fmaf(wgt, bf_lo(p.x), a0);
                a1 = fmaf(wgt, bf_hi(p.x), a1);
                a2 = fmaf(wgt, bf_lo(p.y), a2);
                a3 = fmaf(wgt, bf_hi(p.y), a3);
            }
        }
        float inv = 1.f / (z + 1e-16f);   // z uniform across the 8-lane group
        const float4 bv = *reinterpret_cast<const float4*>(&b2[4 * e]);
        o = make_float4(a0 * inv + bv.x, a1 * inv + bv.y, a2 * inv + bv.z, a3 * inv + bv.w);
        *reinterpret_cast<float4*>(&out[(size_t)wid * 32 + 4 * e]) = o;
    }
    // ---- fused BN2 partials (deterministic tree over the block's 32 node slots) ----
    int ns = wslot * 8 + g;
    red[e][ns][0] = o.x; red[e][ns][1] = o.y; red[e][ns][2] = o.z; red[e][ns][3] = o.w;
    red2[e][ns][0] = o.x * o.x; red2[e][ns][1] = o.y * o.y;
    red2[e][ns][2] = o.z * o.z; red2[e][ns][3] = o.w * o.w;
    __syncthreads();
    for (int step = 16; step > 0; step >>= 1) {
        if (ns < step) {
#pragma unroll
            for (int i = 0; i < 4; i++) {
                red[e][ns][i] += red[e][ns + step][i];
                red2[e][ns][i] += red2[e][ns + step][i];
            }
        }
        __syncthreads();
    }
    if (ns == 0) {
#pragma unroll
        for (int i = 0; i < 4; i++) {
            partials[(size_t)blockIdx.x * 64 + 4 * e + i] = red[e][0][i];
            partials[(size_t)blockIdx.x * 64 + 32 + 4 * e + i] = red2[e][0][i];
        }
    }
}

// ---------------- BN2+ELU + mean pool + classifier: wave per graph (inline bounds) -------
__global__ void k_pool(const float* __restrict__ x, const float* __restrict__ AB2,
                       const int* __restrict__ batch, const float* __restrict__ Wc,
                       const float* __restrict__ bc, float* __restrict__ out, int n, int G_) {
    int wid = (blockIdx.x * blockDim.x + threadIdx.x) >> 6;
    int lane = threadIdx.x & 63;
    if (wid >= G_) return;
    int lo = 0, hi = n;
    while (lo < hi) {
        int mid = (lo + hi) >> 1;
        if (batch[mid] < wid) lo = mid + 1; else hi = mid;
    }
    int beg = lo;
    hi = n;
    while (lo < hi) {
        int mid = (lo + hi) >> 1;
        if (batch[mid] < wid + 1) lo = mid + 1; else hi = mid;
    }
    int end = lo;
    int half = lane >> 5, f = lane & 31;
    float A = AB2[f], B = AB2[32 + f];
    float acc = 0.f;
    for (int r = beg + half; r < end; r += 2) {
        float v = x[(size_t)r * 32 + f] * A + B;
        acc += elu(v);
    }
    acc += __shfl_xor(acc, 32);
    float cntf = (float)((end - beg) > 1 ? (end - beg) : 1);
    float embv = acc / cntf;
    float p0 = embv * Wc[f * 2], p1 = embv * Wc[f * 2 + 1];
#pragma unroll
    for (int o = 1; o < 32; o <<= 1) {
        p0 += __shfl_xor(p0, o);
        p1 += __shfl_xor(p1, o);
    }
    if (lane == 0) {
        out[wid * 2] = p0 + bc[0];
        out[wid * 2 + 1] = p1 + bc[1];
    }
}

extern "C" void kernel_launch(void* const* d_in, const int* in_sizes, int n_in,
                              void* d_out, int out_size, void* d_ws, size_t ws_size,
                              hipStream_t stream) {
    const float* x = (const float*)d_in[0];
    const int* ei = (const int*)d_in[1];
    const int* batch = (const int*)d_in[2];
    const float* W1 = (const float*)d_in[3];
    const float* as1 = (const float*)d_in[4];
    const float* ad1 = (const float*)d_in[5];
    const float* b1 = (const float*)d_in[6];
    const float* g1 = (const float*)d_in[7];
    const float* be1 = (const float*)d_in[8];
    const float* W2 = (const float*)d_in[9];
    const float* as2 = (const float*)d_in[10];
    const float* ad2 = (const float*)d_in[11];
    const float* b2 = (const float*)d_in[12];
    const float* g2 = (const float*)d_in[13];
    const float* be2 = (const float*)d_in[14];
    const float* Wc = (const float*)d_in[15];
    const float* bc = (const float*)d_in[16];
    float* out = (float*)d_out;

    const int N = in_sizes[0] / 2;
    const int E = in_sizes[1] / 2;
    const int G = out_size / 2;
    const int Etot = E + N;
    const int B = (N + 511) >> 9;     // buckets of 512 dst nodes (<= 256)
    const int CH = (E + P - 1) / P;   // edges per radix block
    const int NB1 = (N + 63) / 64;    // agg1f blocks (moment partials)
    const int NB2 = (N + 31) / 32;    // agg2 blocks (BN2 partials)

    // workspace layout
    char* w = (char*)d_ws;
    size_t off = 0;
    auto alloc = [&](size_t bytes) { void* p = w + off; off = (off + bytes + 255) & ~(size_t)255; return p; };
    float* nsum = (float*)alloc((size_t)N * 8 * 4);          // per-node (sx[4], sy[4])
    unsigned* l2buf = (unsigned*)alloc((size_t)N * 50 * 4);  // h2bf + als2 + ald2 + out2
    int* esrc = (int*)alloc((size_t)Etot * 4);
    unsigned* staged = (unsigned*)alloc((size_t)E * 4);
    int* rp = (int*)alloc((size_t)(N + 1) * 4);
    int* ghist = (int*)alloc((size_t)P * BNUM * 4);
    int* goff = (int*)alloc((size_t)P * BNUM * 4);
    int* sbase = (int*)alloc((BNUM + 1) * 4);
    float* partials = (float*)alloc((size_t)NB2 * 64 * 4);
    float* mid = (float*)alloc(64 * 64 * 4);
    float* mpart = (float*)alloc((size_t)NB1 * 20 * 4);
    float* AB2 = (float*)alloc(64 * 4);
    float* MsMd = (float*)alloc(64 * 4);
    float4* PQR = (float4*)alloc(128 * 16);
    unsigned* h2bf = l2buf;                                  // N*16 uints (N x 32 bf16)
    float* als2 = (float*)(l2buf + (size_t)N * 16);          // N floats
    float* ald2 = (float*)(l2buf + (size_t)N * 17);          // N floats
    float* out2 = (float*)(l2buf + (size_t)N * 18);          // N*32 floats

    // 1. tiny prep: factorized attention matrices
    k_prep<<<1, 64, 0, stream>>>(W1, as1, ad1, MsMd);
    // 2. radix pass A: per-block histograms
    k_hist<<<P, 256, 0, stream>>>(ei, ghist, E, CH);
    // 3. radix pass B: bucket-major exclusive scan -> goff, sbase, rp[N]
    k_gscan<<<1, 1024, 0, stream>>>(ghist, goff, sbase, rp, N, E);
    // 4. radix pass C: scatter to block-private ranges
    k_scatter3<<<P, 256, 0, stream>>>(ei, goff, staged, E, CH);
    // 5. per-bucket finalize: rp + esrc (+self loops)
    k_bucket<<<B, 512, 0, stream>>>(staged, sbase, rp, esrc, N);
    // 6. layer 1 aggregation + fused BN1 moment partials
    k_agg1f<<<NB1, 256, 0, stream>>>(x, rp, esrc, MsMd, nsum, mpart, N);
    // 7. BN1 finalize (parallel): per-channel P,Q,R
    k_bn1fin<<<1, 640, 0, stream>>>(mpart, W1, b1, g1, be1, PQR, N, NB1);
    // 8. layer 2 node transform: MFMA (16-node tile per wave)
    k_node2m<<<(N + 63) / 64, 256, 0, stream>>>(nsum, PQR, W2, as2, ad2, h2bf, als2, ald2, N);
    // 9. layer 2 aggregation + fused BN2 partials
    k_agg2<<<NB2, 256, 0, stream>>>(h2bf, als2, ald2, rp, esrc, b2, out2, partials, N);
    // 10. BN2 finalize: parallel stage A (64 blocks) then stage B
    k_red2<<<64, 256, 0, stream>>>(partials, mid, NB2);
    k_stats2<<<1, 512, 0, stream>>>(mid, g2, be2, AB2, N, 32, 64);
    // 11. BN2+ELU + pool + classifier (bounds inline)
    k_pool<<<(G * 64 + 255) / 256, 256, 0, stream>>>(out2, AB2, batch, Wc, bc, out, N, G);
}